// Round 14
// baseline (395.609 us; speedup 1.0000x reference)
//
#include <hip/hip_runtime.h>
#include <hip/hip_bf16.h>
#include <stdint.h>

// B=2, T=2048, D=1024, H=16, hd=64.
// R18 = R17 + (1) qkv reads x DIRECTLY when input is bf16 (sniffs x itself;
// prep's convert blocks become sniff-and-exit; removes 16MB of serial-path
// traffic); f32 path unchanged (convert -> Xb fallback). (2) attn PV dual
// accumulator (oa/ob by sblk parity, summed in epilogue): halves the PV
// chain depth, +32 VGPR (<=128 cap, occupancy preserved).
// attn structure otherwise frozen (local minimum: sched x3 neutral,
// occupancy x2 negative, fusion incorrect per cross-XCD coherence).

typedef unsigned short u16;
typedef short bf16x8 __attribute__((ext_vector_type(8)));
typedef float f32x4  __attribute__((ext_vector_type(4)));
typedef float f32x16 __attribute__((ext_vector_type(16)));

#if defined(__has_builtin) && __has_builtin(__builtin_amdgcn_exp2f)
#define EXP2F(x) __builtin_amdgcn_exp2f(x)
#else
#define EXP2F(x) exp2f(x)
#endif

__device__ __forceinline__ u16 f2b(float f) {           // fp32 -> bf16 RNE
  uint32_t u = __float_as_uint(f);
  u += 0x7fffu + ((u >> 16) & 1u);
  return (u16)(u >> 16);
}
__device__ __forceinline__ uint32_t pkbf(float a, float b) {  // v_cvt_pk_bf16_f32
  __hip_bfloat162 h = __float22bfloat162_rn(make_float2(a, b));
  union { __hip_bfloat162 h2; uint32_t u; } cv; cv.h2 = h;
  return cv.u;
}

// async global->LDS DMA, 16B per lane. LDS dest must be uniform-base + lane*16.
__device__ __forceinline__ void gl2lds16(const void* g, void* l) {
  __builtin_amdgcn_global_load_lds(
      (const __attribute__((address_space(1))) unsigned int*)g,
      (__attribute__((address_space(3))) unsigned int*)l, 16, 0, 0);
}

// ------------------------------------------------- per-block dtype sniff
// Identical sample set + threshold everywhere (first 4096 even u16 slots of
// x) -> every block reaches the same verdict. tid in [0,256).
__device__ __forceinline__ int sniff_x(const void* x, int tid, int* sh) {
  const u16* xu = (const u16*)x;
  if (tid == 0) *sh = 0;
  __syncthreads();
  int c = 0;
  #pragma unroll
  for (int i = 0; i < 16; i++) {
    const int idx = tid + i * 256;
    float a = fabsf(__uint_as_float(((uint32_t)xu[2 * idx]) << 16));
    if (a > 1e-3f && a < 100.f) c++;
  }
  c += __shfl_down(c, 32, 64);
  c += __shfl_down(c, 16, 64);
  c += __shfl_down(c, 8, 64);
  c += __shfl_down(c, 4, 64);
  c += __shfl_down(c, 2, 64);
  c += __shfl_down(c, 1, 64);
  if ((tid & 63) == 0) atomicAdd(sh, c);
  __syncthreads();
  return (*sh > 2048) ? 1 : 0;
}

// ------------------------------------------------- 64x64 transpose helper
__device__ __forceinline__ void tr_tile(const void* src, u16* dst, int Kd, int N,
                                        int n0, int k0, int isb, u16* Lt, int tid)
{
  const int r = tid >> 2, cseg = (tid & 3) << 4;
  u16 t[16];
  if (isb) {
    const u16* s = (const u16*)src + (size_t)(k0 + r) * N + n0 + cseg;
    *(uint4*)&t[0] = *(const uint4*)s;
    *(uint4*)&t[8] = *(const uint4*)(s + 8);
  } else {
    const float* s = (const float*)src + (size_t)(k0 + r) * N + n0 + cseg;
    #pragma unroll
    for (int j = 0; j < 4; j++) {
      float4 v = *(const float4*)(s + j * 4);
      t[j*4+0] = f2b(v.x); t[j*4+1] = f2b(v.y); t[j*4+2] = f2b(v.z); t[j*4+3] = f2b(v.w);
    }
  }
  #pragma unroll
  for (int j = 0; j < 16; j++) Lt[(cseg + j) * 72 + r] = t[j];
  __syncthreads();
  const int n = tid >> 2, kseg = (tid & 3) << 4;
  uint4 u0 = *(const uint4*)&Lt[n * 72 + kseg];
  uint4 u1 = *(const uint4*)&Lt[n * 72 + kseg + 8];
  u16* d = dst + (size_t)(n0 + n) * Kd + k0 + kseg;
  *(uint4*)d = u0;
  *(uint4*)(d + 8) = u1;
}

// ------------------------------------------------- fused prep
// blocks [0,2048): x->bf16 (skipped when x already bf16 -- qkv reads x
// directly) ; [2048,2816): Wqkv^T ; [2816,3072): Wout^T ;
// [3072,3328): RoPE table CS[t*32+f] = {cos,sin}
__global__ __launch_bounds__(256) void prep_kernel(
    const void* __restrict__ x, const void* __restrict__ wqkv,
    const void* __restrict__ wout,
    u16* __restrict__ Xb, u16* __restrict__ Wqkvt, u16* __restrict__ Woutt,
    float2* __restrict__ CS)
{
  __shared__ u16 Lt[64 * 72];
  __shared__ int snf;
  const int bid = blockIdx.x, tid = threadIdx.x;
  if (bid < 2048) {
    const int isb = sniff_x(x, tid, &snf);
    if (!isb) {                         // f32 input: materialize bf16 Xb
      const size_t i = ((size_t)bid * 256 + tid) * 8;
      const float* s = (const float*)x + i;
      float4 a = *(const float4*)s, b = *(const float4*)(s + 4);
      uint4 p;
      p.x = pkbf(a.x, a.y); p.y = pkbf(a.z, a.w);
      p.z = pkbf(b.x, b.y); p.w = pkbf(b.z, b.w);
      *(uint4*)&Xb[i] = p;
    }
  } else if (bid < 2816) {
    const int isb = sniff_x(x, tid, &snf);
    const int b = bid - 2048;
    tr_tile(wqkv, Wqkvt, 1024, 3072, (b % 48) * 64, (b / 48) * 64, isb, Lt, tid);
  } else if (bid < 3072) {
    const int isb = sniff_x(x, tid, &snf);
    const int b = bid - 2816;
    tr_tile(wout, Woutt, 1024, 1024, (b % 16) * 64, (b / 16) * 64, isb, Lt, tid);
  } else {
    const int idx = (bid - 3072) * 256 + tid;   // 65536
    const int t = idx >> 5, f = idx & 31;
    float invf = __expf(-(float)f * 0.2878231366242557f);  // ln(1e4)/32
    float th = (float)t * invf;
    float sn, cs;
    sincosf(th, &sn, &cs);
    CS[idx] = make_float2(cs, sn);
  }
}

// ------------------------------------------------- QKV GEMM (NT, bf16) + RoPE
// Q/K waves accumulate C^T (mfma(bf,af)): lane holds 4 consecutive d at fixed
// t -> in-lane RoPE, float4 CS loads, packed uint2 stores. V waves keep the
// original orientation; V's t-index is stored sigma4-permuted (swap bits 2<->3
// of t&15) to match the attn PV k-order. 1D grid 768, XCD-chunked: each XCD
// owns 4 m-tiles x all 24 n-tiles (A panel 1MB L2-resident). A is staged
// directly from x when x is bf16 (sniffed per block), else from Xb.
__global__ __launch_bounds__(256) void qkv_kernel(
    const void* __restrict__ xraw, const u16* __restrict__ Xb,
    const u16* __restrict__ Wt, const float2* __restrict__ CS,
    u16* __restrict__ Q, u16* __restrict__ K, u16* __restrict__ Vt)
{
  __shared__ u16 As[128 * 64];
  __shared__ u16 Bs[128 * 64];
  __shared__ int snf;
  const int tid = threadIdx.x;
  const int isbx = sniff_x(xraw, tid, &snf);
  const u16* Asrc = isbx ? (const u16*)xraw : Xb;
  const int bidx = blockIdx.x;
  const int swz = (bidx & 7) * 96 + (bidx >> 3);   // XCD-bijective, 96/XCD
  const int n0 = (swz % 24) * 128;
  const int m0 = (swz / 24) * 128;
  const int w = tid >> 6, l = tid & 63, lr = l & 15, lq = l >> 4;
  const int mrow0 = (w & 1) * 64;
  const int ncol0 = (w >> 1) * 64;
  const int srow = tid >> 3;
  const int gseg = (tid & 7) ^ (srow & 7);

  const int col0 = n0 + ncol0;
  const int sec = col0 >> 10;            // 0=q 1=k 2=v
  const int isv = (sec == 2);
  const int h = (col0 >> 6) & 15;

  f32x4 acc[4][4] = {};

  for (int k0 = 0; k0 < 1024; k0 += 64) {
    __syncthreads();
    #pragma unroll
    for (int rd = 0; rd < 4; rd++) {
      const int row = srow + rd * 32;
      gl2lds16(Asrc + (size_t)(m0 + row) * 1024 + k0 + gseg * 8, &As[tid * 8 + rd * 2048]);
      gl2lds16(Wt + (size_t)(n0 + row) * 1024 + k0 + gseg * 8, &Bs[tid * 8 + rd * 2048]);
    }
    __syncthreads();
    #pragma unroll
    for (int kc = 0; kc < 2; kc++) {
      bf16x8 af[4], bf[4];
      #pragma unroll
      for (int i = 0; i < 4; i++) {
        const int seg = ((kc << 2) | lq) ^ (lr & 7);
        af[i] = *(const bf16x8*)&As[(mrow0 + i * 16 + lr) * 64 + seg * 8];
        bf[i] = *(const bf16x8*)&Bs[(ncol0 + i * 16 + lr) * 64 + seg * 8];
      }
      if (isv) {
        #pragma unroll
        for (int mb = 0; mb < 4; mb++)
          #pragma unroll
          for (int nb = 0; nb < 4; nb++)
            acc[mb][nb] = __builtin_amdgcn_mfma_f32_16x16x32_bf16(af[mb], bf[nb], acc[mb][nb], 0, 0, 0);
      } else {
        // transposed: rows = n (d), cols = m (t)
        #pragma unroll
        for (int mb = 0; mb < 4; mb++)
          #pragma unroll
          for (int nb = 0; nb < 4; nb++)
            acc[mb][nb] = __builtin_amdgcn_mfma_f32_16x16x32_bf16(bf[nb], af[mb], acc[mb][nb], 0, 0, 0);
      }
    }
  }

  if (isv) {
    #pragma unroll
    for (int mb = 0; mb < 4; mb++) {
      const int row0 = m0 + mrow0 + mb * 16 + lq * 4;
      const int b = row0 >> 11, t0 = row0 & 2047;
      // sigma4: swap bits 2 and 3 of t (t0 is a multiple of 4):
      const int tp = (t0 & ~12) | ((t0 & 4) << 1) | ((t0 & 8) >> 1);
      #pragma unroll
      for (int nb = 0; nb < 4; nb++) {
        const int d = nb * 16 + lr;
        uint2 uv;
        uv.x = pkbf(acc[mb][nb][0], acc[mb][nb][1]);
        uv.y = pkbf(acc[mb][nb][2], acc[mb][nb][3]);
        *(uint2*)&Vt[(((size_t)b * 16 + h) * 64 + d) * 2048 + tp] = uv;
      }
    }
  } else {
    u16* dst = (sec == 0) ? Q : K;
    const float qscale = 0.125f * 1.44269504f;   // 1/sqrt(hd) * log2(e), q only
    #pragma unroll
    for (int mb = 0; mb < 4; mb++) {
      const int m = m0 + mrow0 + mb * 16 + lr;   // global row = b*2048 + t
      const int b = m >> 11, t = m & 2047;
      const float* csrow = (const float*)(CS + t * 32);
      #pragma unroll
      for (int nb = 0; nb < 4; nb++) {
        const int d = nb * 16 + lq * 4;          // 4 consecutive d, d%4==0
        const int fb = d & 31;                   // pair block stays within 32
        f32x4 c01 = *(const f32x4*)(csrow + 2 * fb);      // {c0,s0,c1,s1}
        f32x4 c23 = *(const f32x4*)(csrow + 2 * fb + 4);  // {c2,s2,c3,s3}
        float v0 = acc[mb][nb][0], v1 = acc[mb][nb][1];
        float v2 = acc[mb][nb][2], v3 = acc[mb][nb][3];
        float r0 = v0 * c01[0] - v1 * c01[1];
        float r1 = fmaf(v1, c01[2], v0 * c01[3]);
        float r2 = v2 * c23[0] - v3 * c23[1];
        float r3 = fmaf(v3, c23[2], v2 * c23[3]);
        if (sec == 0) { r0 *= qscale; r1 *= qscale; r2 *= qscale; r3 *= qscale; }
        uint2 uv;
        uv.x = pkbf(r0, r1);
        uv.y = pkbf(r2, r3);
        *(uint2*)&dst[(((size_t)b * 16 + h) * 2048 + t) * 64 + d] = uv;
      }
    }
  }
}

// ------------------------------------------------- MFMA flash attention (R18)
// Block = 8 waves (512 thr): shard = wave>>2 picks the s-half; subwave ws =
// wave&3 picks 32 q-rows of the block's 128. Each shard double-buffers its
// own K/V (pool 64KB). 32x32x16 MFMA, lane owns one q-row; sigma4-permuted
// Vt makes S^T C-regs the PV B-operand. PV uses dual accumulators (oa/ob by
// sblk parity, summed in epilogue) to halve the chain depth. LDS merge -> ATT.
__global__ __launch_bounds__(512, 4) void attn_kernel(
    const u16* __restrict__ Q, const u16* __restrict__ K,
    const u16* __restrict__ Vt, u16* __restrict__ ATT)
{
  __shared__ u16 pool[2][2][2][4096];   // [shard][K=0/V=1][buf][64*64] = 64KB
  const int tid = threadIdx.x;          // 0..511
  const int shard = tid >> 8;
  const int t2 = tid & 255;             // tid within shard
  const int ws = (tid >> 6) & 3;        // subwave (q-group)
  const int l = tid & 63;
  const int m5 = l & 31, hi = l >> 5;

  // XCD-bijective swizzle: grid 512 = 32 bh x 16 qt; 64 consecutive work ids
  // (4 bh) per XCD.
  const int bid = blockIdx.x;
  const int swz = (bid & 7) * 64 + (bid >> 3);
  const int bh = swz >> 4;
  const int qt = swz & 15;

  const int sbeg = shard * 1024;        // this shard's s-range
  const size_t base = (size_t)bh * (2048 * 64);
  const int qrow0 = qt * 128 + ws * 32;
  const int t_own = qrow0 + m5;         // this lane's q-row

  // Q fragments (B-operand: col = m5, k-slot hi*8+j = d kd*16+hi*8+j)
  bf16x8 qf[4];
  #pragma unroll
  for (int kd = 0; kd < 4; kd++)
    qf[kd] = *(const bf16x8*)(Q + base + (size_t)t_own * 64 + kd * 16 + hi * 8);

  f32x16 oa[2] = {};                    // O^T partial, even sblk
  f32x16 ob[2] = {};                    // O^T partial, odd sblk
  float lsum = 0.f;

  const int srow = t2 >> 3;

  auto stage = [&](int buf, int s0) {
    #pragma unroll
    for (int rd = 0; rd < 2; rd++) {
      const int row = srow + rd * 32;
      const int gs = (t2 & 7) ^ (row & 7) ^ ((row >> 3) & 3);
      gl2lds16(K + base + (size_t)(s0 + row) * 64 + gs * 8,
               &pool[shard][0][buf][t2 * 8 + rd * 2048]);
      gl2lds16(Vt + base + (size_t)row * 2048 + s0 + gs * 8,
               &pool[shard][1][buf][t2 * 8 + rd * 2048]);
    }
  };

  stage(0, sbeg);
  const int nt = 16;

  #pragma unroll 1
  for (int t = 0; t < nt; t++) {
    const int buf = t & 1;
    __syncthreads();                    // drains DMA for buf, fences prev reads
    if (t + 1 < nt) stage(buf ^ 1, sbeg + (t + 1) * 64);
    const u16* Ks = pool[shard][0][buf];
    const u16* Vs = pool[shard][1][buf];

    // ---- S phase: per s-block of 32, kf row = sb*32+m5, d-seg (kd<<1)|hi
    uint32_t pw[2][8];
    #pragma unroll
    for (int sb = 0; sb < 2; sb++) {
      const int row = sb * 32 + m5;
      const int sw = (row & 7) ^ ((row >> 3) & 3);
      bf16x8 kf[4];
      #pragma unroll
      for (int kd = 0; kd < 4; kd++)
        kf[kd] = *(const bf16x8*)&Ks[row * 64 + ((((kd << 1) | hi) ^ sw) << 3)];
      f32x16 z = {};
      __builtin_amdgcn_s_setprio(1);
      z = __builtin_amdgcn_mfma_f32_32x32x16_bf16(kf[0], qf[0], z, 0, 0, 0);
      z = __builtin_amdgcn_mfma_f32_32x32x16_bf16(kf[1], qf[1], z, 0, 0, 0);
      z = __builtin_amdgcn_mfma_f32_32x32x16_bf16(kf[2], qf[2], z, 0, 0, 0);
      z = __builtin_amdgcn_mfma_f32_32x32x16_bf16(kf[3], qf[3], z, 0, 0, 0);
      __builtin_amdgcn_s_setprio(0);
      float e[16];
      #pragma unroll
      for (int r = 0; r < 16; r++) e[r] = EXP2F(z[r]);
      lsum += (((e[0] + e[1]) + (e[2] + e[3])) + ((e[4] + e[5]) + (e[6] + e[7])))
            + (((e[8] + e[9]) + (e[10] + e[11])) + ((e[12] + e[13]) + (e[14] + e[15])));
      #pragma unroll
      for (int w2 = 0; w2 < 8; w2++)
        pw[sb][w2] = pkbf(e[2 * w2], e[2 * w2 + 1]);
    }

    // ---- PV phase: vf row = db*32+m5, t-seg (sblk<<1)|hi (sigma4-linear).
    // Dual accumulators: even sblk -> oa, odd sblk -> ob (halved chain).
    #pragma unroll
    for (int db = 0; db < 2; db++) {
      const int row = db * 32 + m5;
      const int sw = (row & 7) ^ ((row >> 3) & 3);
      bf16x8 vf[4];
      #pragma unroll
      for (int sblk = 0; sblk < 4; sblk++)
        vf[sblk] = *(const bf16x8*)&Vs[row * 64 + ((((sblk << 1) | hi) ^ sw) << 3)];
      union { uint32_t u[4]; bf16x8 v; } pf0, pf1, pf2, pf3;
      pf0.u[0] = pw[0][0]; pf0.u[1] = pw[0][1]; pf0.u[2] = pw[0][2]; pf0.u[3] = pw[0][3];
      pf1.u[0] = pw[0][4]; pf1.u[1] = pw[0][5]; pf1.u[2] = pw[0][6]; pf1.u[3] = pw[0][7];
      pf2.u[0] = pw[1][0]; pf2.u[1] = pw[1][1]; pf2.u[2] = pw[1][2]; pf2.u[3] = pw[1][3];
      pf3.u[0] = pw[1][4]; pf3.u[1] = pw[1][5]; pf3.u[2] = pw[1][6]; pf3.u[3] = pw[1][7];
      __builtin_amdgcn_s_setprio(1);
      oa[db] = __builtin_amdgcn_mfma_f32_32x32x16_bf16(vf[0], pf0.v, oa[db], 0, 0, 0);
      ob[db] = __builtin_amdgcn_mfma_f32_32x32x16_bf16(vf[1], pf1.v, ob[db], 0, 0, 0);
      oa[db] = __builtin_amdgcn_mfma_f32_32x32x16_bf16(vf[2], pf2.v, oa[db], 0, 0, 0);
      ob[db] = __builtin_amdgcn_mfma_f32_32x32x16_bf16(vf[3], pf3.v, ob[db], 0, 0, 0);
      __builtin_amdgcn_s_setprio(0);
    }
  }

  // fold dual accumulators, reduce row sum across the hi pair
  oa[0] += ob[0];
  oa[1] += ob[1];
  lsum += __shfl_xor(lsum, 32, 64);

  // ---- in-block merge: shard 1 dumps partials to LDS, shard 0 combines.
  // Layout mo[(ws*32 + r)*64 + lane] (lane-contiguous -> conflict-free);
  // lsum at float offset 8192 + ws*64 + lane. 33KB < 64KB pool.
  float* mo = (float*)pool;
  __syncthreads();                      // all tile reads done; pool reusable
  if (shard == 1) {
    #pragma unroll
    for (int db = 0; db < 2; db++)
      #pragma unroll
      for (int r = 0; r < 16; r++)
        mo[((ws * 32 + db * 16 + r) << 6) + l] = oa[db][r];
    mo[8192 + ws * 64 + l] = lsum;
  }
  __syncthreads();
  if (shard == 0) {
    const float ls2 = mo[8192 + ws * 64 + l];
    const float inv = 1.f / (lsum + ls2);
    const int b = bh >> 4, h = bh & 15;
    u16* dst = ATT + ((size_t)(b * 2048 + t_own)) * 1024 + h * 64;
    #pragma unroll
    for (int db = 0; db < 2; db++)
      #pragma unroll
      for (int rq = 0; rq < 4; rq++) {
        const int d0 = db * 32 + rq * 8 + hi * 4;
        float s0 = oa[db][4 * rq + 0] + mo[((ws * 32 + db * 16 + 4 * rq + 0) << 6) + l];
        float s1 = oa[db][4 * rq + 1] + mo[((ws * 32 + db * 16 + 4 * rq + 1) << 6) + l];
        float s2 = oa[db][4 * rq + 2] + mo[((ws * 32 + db * 16 + 4 * rq + 2) << 6) + l];
        float s3 = oa[db][4 * rq + 3] + mo[((ws * 32 + db * 16 + 4 * rq + 3) << 6) + l];
        uint2 u;
        u.x = pkbf(s0 * inv, s1 * inv);
        u.y = pkbf(s2 * inv, s3 * inv);
        *(uint2*)&dst[d0] = u;
      }
  }
}

// ------------------------------------------------- output projection (NT, bf16)
// Transposed accumulators throughout: lane holds 4 consecutive cols at fixed
// row -> vector stores (f32x4 or packed uint2). 1D grid 256, XCD-chunked:
// each XCD owns one n-tile x all 32 m-tiles (Woutt panel 256KB L2-resident).
__global__ __launch_bounds__(256) void outproj_kernel(
    const u16* __restrict__ A, const u16* __restrict__ Wt,
    const void* __restrict__ xprobe, void* __restrict__ outv)
{
  __shared__ u16 As[128 * 64];
  __shared__ u16 Bs[128 * 64];
  __shared__ int snf;
  const int tid = threadIdx.x;
  const int isb = sniff_x(xprobe, tid, &snf);
  const int bidx = blockIdx.x;
  const int n0 = (bidx & 7) * 128;      // XCD owns one n-tile
  const int m0 = (bidx >> 3) * 128;
  const int w = tid >> 6, l = tid & 63, lr = l & 15, lq = l >> 4;
  const int mrow0 = (w & 1) * 64;
  const int ncol0 = (w >> 1) * 64;
  const int srow = tid >> 3;
  const int gseg = (tid & 7) ^ (srow & 7);

  f32x4 acc[4][4] = {};

  for (int k0 = 0; k0 < 1024; k0 += 64) {
    __syncthreads();
    #pragma unroll
    for (int rd = 0; rd < 4; rd++) {
      const int row = srow + rd * 32;
      gl2lds16(A + (size_t)(m0 + row) * 1024 + k0 + gseg * 8, &As[tid * 8 + rd * 2048]);
      gl2lds16(Wt + (size_t)(n0 + row) * 1024 + k0 + gseg * 8, &Bs[tid * 8 + rd * 2048]);
    }
    __syncthreads();
    #pragma unroll
    for (int kc = 0; kc < 2; kc++) {
      bf16x8 af[4], bf[4];
      #pragma unroll
      for (int i = 0; i < 4; i++) {
        const int seg = ((kc << 2) | lq) ^ (lr & 7);
        af[i] = *(const bf16x8*)&As[(mrow0 + i * 16 + lr) * 64 + seg * 8];
        bf[i] = *(const bf16x8*)&Bs[(ncol0 + i * 16 + lr) * 64 + seg * 8];
      }
      #pragma unroll
      for (int mb = 0; mb < 4; mb++)
        #pragma unroll
        for (int nb = 0; nb < 4; nb++)
          acc[mb][nb] = __builtin_amdgcn_mfma_f32_16x16x32_bf16(bf[nb], af[mb], acc[mb][nb], 0, 0, 0);
    }
  }
  #pragma unroll
  for (int mb = 0; mb < 4; mb++) {
    const int row = m0 + mrow0 + mb * 16 + lr;
    #pragma unroll
    for (int nb = 0; nb < 4; nb++) {
      const int col = n0 + ncol0 + nb * 16 + lq * 4;
      f32x4 v = acc[mb][nb];
      if (isb) {
        uint2 uv;
        uv.x = pkbf(v[0], v[1]);
        uv.y = pkbf(v[2], v[3]);
        *(uint2*)&((u16*)outv)[(size_t)row * 1024 + col] = uv;
      } else {
        *(f32x4*)&((float*)outv)[(size_t)row * 1024 + col] = v;
      }
    }
  }
}

extern "C" void kernel_launch(void* const* d_in, const int* in_sizes, int n_in,
                              void* d_out, int out_size, void* d_ws, size_t ws_size,
                              hipStream_t stream)
{
  const void* x    = d_in[0];
  const void* wqkv = d_in[1];
  const void* wout = d_in[2];
  char* ws = (char*)d_ws;
  const size_t MB = 1024 * 1024;
  float2* CS     = (float2*)(ws + 1024);            // 512 KB
  u16*    Xb     = (u16*)(ws + 1 * MB);             // 8 MB  (aliased by ATT)
  u16*    ATT    = Xb;
  u16*    Wqkvt  = (u16*)(ws + 9 * MB);             // 6 MB
  u16*    Woutt  = (u16*)(ws + 15 * MB);            // 2 MB
  u16*    Q      = (u16*)(ws + 17 * MB);            // 8 MB
  u16*    K      = (u16*)(ws + 25 * MB);            // 8 MB
  u16*    Vt     = (u16*)(ws + 33 * MB);            // 8 MB

  prep_kernel<<<3328, 256, 0, stream>>>(x, wqkv, wout, Xb, Wqkvt, Woutt, CS);
  qkv_kernel<<<dim3(768), 256, 0, stream>>>(x, Xb, Wqkvt, CS, Q, K, Vt);
  attn_kernel<<<dim3(512), 512, 0, stream>>>(Q, K, Vt, ATT);
  outproj_kernel<<<dim3(256), 256, 0, stream>>>(ATT, Woutt, x, d_out);
}

// Round 15
// 196.283 us; speedup vs baseline: 2.0155x; 2.0155x over previous
//
#include <hip/hip_runtime.h>
#include <hip/hip_bf16.h>
#include <stdint.h>

// B=2, T=2048, D=1024, H=16, hd=64.
// R19 = R17's attn (proven 64-VGPR body; R18's dual-accumulator spilled --
// launch_bounds(512,4) pins the allocator at 64 VGPR and extra live state
// goes to scratch: 629MB writes, 5x slowdown) + R18's validated prep/qkv
// change (qkv stages A directly from x when bf16; prep convert blocks
// sniff-and-exit; removes ~16MB serial-path traffic).

typedef unsigned short u16;
typedef short bf16x8 __attribute__((ext_vector_type(8)));
typedef float f32x4  __attribute__((ext_vector_type(4)));
typedef float f32x16 __attribute__((ext_vector_type(16)));

#if defined(__has_builtin) && __has_builtin(__builtin_amdgcn_exp2f)
#define EXP2F(x) __builtin_amdgcn_exp2f(x)
#else
#define EXP2F(x) exp2f(x)
#endif

__device__ __forceinline__ u16 f2b(float f) {           // fp32 -> bf16 RNE
  uint32_t u = __float_as_uint(f);
  u += 0x7fffu + ((u >> 16) & 1u);
  return (u16)(u >> 16);
}
__device__ __forceinline__ uint32_t pkbf(float a, float b) {  // v_cvt_pk_bf16_f32
  __hip_bfloat162 h = __float22bfloat162_rn(make_float2(a, b));
  union { __hip_bfloat162 h2; uint32_t u; } cv; cv.h2 = h;
  return cv.u;
}

// async global->LDS DMA, 16B per lane. LDS dest must be uniform-base + lane*16.
__device__ __forceinline__ void gl2lds16(const void* g, void* l) {
  __builtin_amdgcn_global_load_lds(
      (const __attribute__((address_space(1))) unsigned int*)g,
      (__attribute__((address_space(3))) unsigned int*)l, 16, 0, 0);
}

// ------------------------------------------------- per-block dtype sniff
// Identical sample set + threshold everywhere (first 4096 even u16 slots of
// x) -> every block reaches the same verdict. tid in [0,256).
__device__ __forceinline__ int sniff_x(const void* x, int tid, int* sh) {
  const u16* xu = (const u16*)x;
  if (tid == 0) *sh = 0;
  __syncthreads();
  int c = 0;
  #pragma unroll
  for (int i = 0; i < 16; i++) {
    const int idx = tid + i * 256;
    float a = fabsf(__uint_as_float(((uint32_t)xu[2 * idx]) << 16));
    if (a > 1e-3f && a < 100.f) c++;
  }
  c += __shfl_down(c, 32, 64);
  c += __shfl_down(c, 16, 64);
  c += __shfl_down(c, 8, 64);
  c += __shfl_down(c, 4, 64);
  c += __shfl_down(c, 2, 64);
  c += __shfl_down(c, 1, 64);
  if ((tid & 63) == 0) atomicAdd(sh, c);
  __syncthreads();
  return (*sh > 2048) ? 1 : 0;
}

// ------------------------------------------------- 64x64 transpose helper
__device__ __forceinline__ void tr_tile(const void* src, u16* dst, int Kd, int N,
                                        int n0, int k0, int isb, u16* Lt, int tid)
{
  const int r = tid >> 2, cseg = (tid & 3) << 4;
  u16 t[16];
  if (isb) {
    const u16* s = (const u16*)src + (size_t)(k0 + r) * N + n0 + cseg;
    *(uint4*)&t[0] = *(const uint4*)s;
    *(uint4*)&t[8] = *(const uint4*)(s + 8);
  } else {
    const float* s = (const float*)src + (size_t)(k0 + r) * N + n0 + cseg;
    #pragma unroll
    for (int j = 0; j < 4; j++) {
      float4 v = *(const float4*)(s + j * 4);
      t[j*4+0] = f2b(v.x); t[j*4+1] = f2b(v.y); t[j*4+2] = f2b(v.z); t[j*4+3] = f2b(v.w);
    }
  }
  #pragma unroll
  for (int j = 0; j < 16; j++) Lt[(cseg + j) * 72 + r] = t[j];
  __syncthreads();
  const int n = tid >> 2, kseg = (tid & 3) << 4;
  uint4 u0 = *(const uint4*)&Lt[n * 72 + kseg];
  uint4 u1 = *(const uint4*)&Lt[n * 72 + kseg + 8];
  u16* d = dst + (size_t)(n0 + n) * Kd + k0 + kseg;
  *(uint4*)d = u0;
  *(uint4*)(d + 8) = u1;
}

// ------------------------------------------------- fused prep
// blocks [0,2048): x->bf16 (skipped when x already bf16 -- qkv reads x
// directly) ; [2048,2816): Wqkv^T ; [2816,3072): Wout^T ;
// [3072,3328): RoPE table CS[t*32+f] = {cos,sin}
__global__ __launch_bounds__(256) void prep_kernel(
    const void* __restrict__ x, const void* __restrict__ wqkv,
    const void* __restrict__ wout,
    u16* __restrict__ Xb, u16* __restrict__ Wqkvt, u16* __restrict__ Woutt,
    float2* __restrict__ CS)
{
  __shared__ u16 Lt[64 * 72];
  __shared__ int snf;
  const int bid = blockIdx.x, tid = threadIdx.x;
  if (bid < 2048) {
    const int isb = sniff_x(x, tid, &snf);
    if (!isb) {                         // f32 input: materialize bf16 Xb
      const size_t i = ((size_t)bid * 256 + tid) * 8;
      const float* s = (const float*)x + i;
      float4 a = *(const float4*)s, b = *(const float4*)(s + 4);
      uint4 p;
      p.x = pkbf(a.x, a.y); p.y = pkbf(a.z, a.w);
      p.z = pkbf(b.x, b.y); p.w = pkbf(b.z, b.w);
      *(uint4*)&Xb[i] = p;
    }
  } else if (bid < 2816) {
    const int isb = sniff_x(x, tid, &snf);
    const int b = bid - 2048;
    tr_tile(wqkv, Wqkvt, 1024, 3072, (b % 48) * 64, (b / 48) * 64, isb, Lt, tid);
  } else if (bid < 3072) {
    const int isb = sniff_x(x, tid, &snf);
    const int b = bid - 2816;
    tr_tile(wout, Woutt, 1024, 1024, (b % 16) * 64, (b / 16) * 64, isb, Lt, tid);
  } else {
    const int idx = (bid - 3072) * 256 + tid;   // 65536
    const int t = idx >> 5, f = idx & 31;
    float invf = __expf(-(float)f * 0.2878231366242557f);  // ln(1e4)/32
    float th = (float)t * invf;
    float sn, cs;
    sincosf(th, &sn, &cs);
    CS[idx] = make_float2(cs, sn);
  }
}

// ------------------------------------------------- QKV GEMM (NT, bf16) + RoPE
// Q/K waves accumulate C^T (mfma(bf,af)): lane holds 4 consecutive d at fixed
// t -> in-lane RoPE, float4 CS loads, packed uint2 stores. V waves keep the
// original orientation; V's t-index is stored sigma4-permuted (swap bits 2<->3
// of t&15) to match the attn PV k-order. 1D grid 768, XCD-chunked: each XCD
// owns 4 m-tiles x all 24 n-tiles (A panel 1MB L2-resident). A is staged
// directly from x when x is bf16 (sniffed per block), else from Xb.
__global__ __launch_bounds__(256) void qkv_kernel(
    const void* __restrict__ xraw, const u16* __restrict__ Xb,
    const u16* __restrict__ Wt, const float2* __restrict__ CS,
    u16* __restrict__ Q, u16* __restrict__ K, u16* __restrict__ Vt)
{
  __shared__ u16 As[128 * 64];
  __shared__ u16 Bs[128 * 64];
  __shared__ int snf;
  const int tid = threadIdx.x;
  const int isbx = sniff_x(xraw, tid, &snf);
  const u16* Asrc = isbx ? (const u16*)xraw : Xb;
  const int bidx = blockIdx.x;
  const int swz = (bidx & 7) * 96 + (bidx >> 3);   // XCD-bijective, 96/XCD
  const int n0 = (swz % 24) * 128;
  const int m0 = (swz / 24) * 128;
  const int w = tid >> 6, l = tid & 63, lr = l & 15, lq = l >> 4;
  const int mrow0 = (w & 1) * 64;
  const int ncol0 = (w >> 1) * 64;
  const int srow = tid >> 3;
  const int gseg = (tid & 7) ^ (srow & 7);

  const int col0 = n0 + ncol0;
  const int sec = col0 >> 10;            // 0=q 1=k 2=v
  const int isv = (sec == 2);
  const int h = (col0 >> 6) & 15;

  f32x4 acc[4][4] = {};

  for (int k0 = 0; k0 < 1024; k0 += 64) {
    __syncthreads();
    #pragma unroll
    for (int rd = 0; rd < 4; rd++) {
      const int row = srow + rd * 32;
      gl2lds16(Asrc + (size_t)(m0 + row) * 1024 + k0 + gseg * 8, &As[tid * 8 + rd * 2048]);
      gl2lds16(Wt + (size_t)(n0 + row) * 1024 + k0 + gseg * 8, &Bs[tid * 8 + rd * 2048]);
    }
    __syncthreads();
    #pragma unroll
    for (int kc = 0; kc < 2; kc++) {
      bf16x8 af[4], bf[4];
      #pragma unroll
      for (int i = 0; i < 4; i++) {
        const int seg = ((kc << 2) | lq) ^ (lr & 7);
        af[i] = *(const bf16x8*)&As[(mrow0 + i * 16 + lr) * 64 + seg * 8];
        bf[i] = *(const bf16x8*)&Bs[(ncol0 + i * 16 + lr) * 64 + seg * 8];
      }
      if (isv) {
        #pragma unroll
        for (int mb = 0; mb < 4; mb++)
          #pragma unroll
          for (int nb = 0; nb < 4; nb++)
            acc[mb][nb] = __builtin_amdgcn_mfma_f32_16x16x32_bf16(af[mb], bf[nb], acc[mb][nb], 0, 0, 0);
      } else {
        // transposed: rows = n (d), cols = m (t)
        #pragma unroll
        for (int mb = 0; mb < 4; mb++)
          #pragma unroll
          for (int nb = 0; nb < 4; nb++)
            acc[mb][nb] = __builtin_amdgcn_mfma_f32_16x16x32_bf16(bf[nb], af[mb], acc[mb][nb], 0, 0, 0);
      }
    }
  }

  if (isv) {
    #pragma unroll
    for (int mb = 0; mb < 4; mb++) {
      const int row0 = m0 + mrow0 + mb * 16 + lq * 4;
      const int b = row0 >> 11, t0 = row0 & 2047;
      // sigma4: swap bits 2 and 3 of t (t0 is a multiple of 4):
      const int tp = (t0 & ~12) | ((t0 & 4) << 1) | ((t0 & 8) >> 1);
      #pragma unroll
      for (int nb = 0; nb < 4; nb++) {
        const int d = nb * 16 + lr;
        uint2 uv;
        uv.x = pkbf(acc[mb][nb][0], acc[mb][nb][1]);
        uv.y = pkbf(acc[mb][nb][2], acc[mb][nb][3]);
        *(uint2*)&Vt[(((size_t)b * 16 + h) * 64 + d) * 2048 + tp] = uv;
      }
    }
  } else {
    u16* dst = (sec == 0) ? Q : K;
    const float qscale = 0.125f * 1.44269504f;   // 1/sqrt(hd) * log2(e), q only
    #pragma unroll
    for (int mb = 0; mb < 4; mb++) {
      const int m = m0 + mrow0 + mb * 16 + lr;   // global row = b*2048 + t
      const int b = m >> 11, t = m & 2047;
      const float* csrow = (const float*)(CS + t * 32);
      #pragma unroll
      for (int nb = 0; nb < 4; nb++) {
        const int d = nb * 16 + lq * 4;          // 4 consecutive d, d%4==0
        const int fb = d & 31;                   // pair block stays within 32
        f32x4 c01 = *(const f32x4*)(csrow + 2 * fb);      // {c0,s0,c1,s1}
        f32x4 c23 = *(const f32x4*)(csrow + 2 * fb + 4);  // {c2,s2,c3,s3}
        float v0 = acc[mb][nb][0], v1 = acc[mb][nb][1];
        float v2 = acc[mb][nb][2], v3 = acc[mb][nb][3];
        float r0 = v0 * c01[0] - v1 * c01[1];
        float r1 = fmaf(v1, c01[2], v0 * c01[3]);
        float r2 = v2 * c23[0] - v3 * c23[1];
        float r3 = fmaf(v3, c23[2], v2 * c23[3]);
        if (sec == 0) { r0 *= qscale; r1 *= qscale; r2 *= qscale; r3 *= qscale; }
        uint2 uv;
        uv.x = pkbf(r0, r1);
        uv.y = pkbf(r2, r3);
        *(uint2*)&dst[(((size_t)b * 16 + h) * 2048 + t) * 64 + d] = uv;
      }
    }
  }
}

// ------------------------------------------------- MFMA flash attention (R12)
// Block = 8 waves (512 thr): shard = wave>>2 picks the s-half; subwave ws =
// wave&3 picks 32 q-rows of the block's 128. Each shard double-buffers its
// own K/V (pool 64KB). 32x32x16 MFMA, lane owns one q-row; sigma4-permuted
// Vt makes S^T C-regs the PV B-operand. Partials merged via LDS -> ATT.
// NOTE: live state exactly fits the 64-VGPR budget this launch_bounds pins;
// any additional accumulator state spills to scratch (R18: 5x slowdown).
__global__ __launch_bounds__(512, 4) void attn_kernel(
    const u16* __restrict__ Q, const u16* __restrict__ K,
    const u16* __restrict__ Vt, u16* __restrict__ ATT)
{
  __shared__ u16 pool[2][2][2][4096];   // [shard][K=0/V=1][buf][64*64] = 64KB
  const int tid = threadIdx.x;          // 0..511
  const int shard = tid >> 8;
  const int t2 = tid & 255;             // tid within shard
  const int ws = (tid >> 6) & 3;        // subwave (q-group)
  const int l = tid & 63;
  const int m5 = l & 31, hi = l >> 5;

  // XCD-bijective swizzle: grid 512 = 32 bh x 16 qt; 64 consecutive work ids
  // (4 bh) per XCD.
  const int bid = blockIdx.x;
  const int swz = (bid & 7) * 64 + (bid >> 3);
  const int bh = swz >> 4;
  const int qt = swz & 15;

  const int sbeg = shard * 1024;        // this shard's s-range
  const size_t base = (size_t)bh * (2048 * 64);
  const int qrow0 = qt * 128 + ws * 32;
  const int t_own = qrow0 + m5;         // this lane's q-row

  // Q fragments (B-operand: col = m5, k-slot hi*8+j = d kd*16+hi*8+j)
  bf16x8 qf[4];
  #pragma unroll
  for (int kd = 0; kd < 4; kd++)
    qf[kd] = *(const bf16x8*)(Q + base + (size_t)t_own * 64 + kd * 16 + hi * 8);

  f32x16 oa[2] = {};                    // O^T partial: rows d = db*32+C-row
  float lsum = 0.f;

  const int srow = t2 >> 3;

  auto stage = [&](int buf, int s0) {
    #pragma unroll
    for (int rd = 0; rd < 2; rd++) {
      const int row = srow + rd * 32;
      const int gs = (t2 & 7) ^ (row & 7) ^ ((row >> 3) & 3);
      gl2lds16(K + base + (size_t)(s0 + row) * 64 + gs * 8,
               &pool[shard][0][buf][t2 * 8 + rd * 2048]);
      gl2lds16(Vt + base + (size_t)row * 2048 + s0 + gs * 8,
               &pool[shard][1][buf][t2 * 8 + rd * 2048]);
    }
  };

  stage(0, sbeg);
  const int nt = 16;

  #pragma unroll 1
  for (int t = 0; t < nt; t++) {
    const int buf = t & 1;
    __syncthreads();                    // drains DMA for buf, fences prev reads
    if (t + 1 < nt) stage(buf ^ 1, sbeg + (t + 1) * 64);
    const u16* Ks = pool[shard][0][buf];
    const u16* Vs = pool[shard][1][buf];

    // ---- S phase: per s-block of 32, kf row = sb*32+m5, d-seg (kd<<1)|hi
    uint32_t pw[2][8];
    #pragma unroll
    for (int sb = 0; sb < 2; sb++) {
      const int row = sb * 32 + m5;
      const int sw = (row & 7) ^ ((row >> 3) & 3);
      bf16x8 kf[4];
      #pragma unroll
      for (int kd = 0; kd < 4; kd++)
        kf[kd] = *(const bf16x8*)&Ks[row * 64 + ((((kd << 1) | hi) ^ sw) << 3)];
      f32x16 z = {};
      __builtin_amdgcn_s_setprio(1);
      z = __builtin_amdgcn_mfma_f32_32x32x16_bf16(kf[0], qf[0], z, 0, 0, 0);
      z = __builtin_amdgcn_mfma_f32_32x32x16_bf16(kf[1], qf[1], z, 0, 0, 0);
      z = __builtin_amdgcn_mfma_f32_32x32x16_bf16(kf[2], qf[2], z, 0, 0, 0);
      z = __builtin_amdgcn_mfma_f32_32x32x16_bf16(kf[3], qf[3], z, 0, 0, 0);
      __builtin_amdgcn_s_setprio(0);
      float e[16];
      #pragma unroll
      for (int r = 0; r < 16; r++) e[r] = EXP2F(z[r]);
      lsum += (((e[0] + e[1]) + (e[2] + e[3])) + ((e[4] + e[5]) + (e[6] + e[7])))
            + (((e[8] + e[9]) + (e[10] + e[11])) + ((e[12] + e[13]) + (e[14] + e[15])));
      #pragma unroll
      for (int w2 = 0; w2 < 8; w2++)
        pw[sb][w2] = pkbf(e[2 * w2], e[2 * w2 + 1]);
    }

    // ---- PV phase: vf row = db*32+m5, t-seg (sblk<<1)|hi (sigma4-linear)
    #pragma unroll
    for (int db = 0; db < 2; db++) {
      const int row = db * 32 + m5;
      const int sw = (row & 7) ^ ((row >> 3) & 3);
      bf16x8 vf[4];
      #pragma unroll
      for (int sblk = 0; sblk < 4; sblk++)
        vf[sblk] = *(const bf16x8*)&Vs[row * 64 + ((((sblk << 1) | hi) ^ sw) << 3)];
      __builtin_amdgcn_s_setprio(1);
      #pragma unroll
      for (int sblk = 0; sblk < 4; sblk++) {
        union { uint32_t u[4]; bf16x8 v; } pf;
        const int sb = sblk >> 1, off = (sblk & 1) * 4;
        pf.u[0] = pw[sb][off + 0]; pf.u[1] = pw[sb][off + 1];
        pf.u[2] = pw[sb][off + 2]; pf.u[3] = pw[sb][off + 3];
        oa[db] = __builtin_amdgcn_mfma_f32_32x32x16_bf16(vf[sblk], pf.v, oa[db], 0, 0, 0);
      }
      __builtin_amdgcn_s_setprio(0);
    }
  }

  // reduce row sum across the hi pair (lanes l and l+32 share t_own)
  lsum += __shfl_xor(lsum, 32, 64);

  // ---- in-block merge: shard 1 dumps partials to LDS, shard 0 combines.
  // Layout mo[(ws*32 + r)*64 + lane] (lane-contiguous -> conflict-free);
  // lsum at float offset 8192 + ws*64 + lane. 33KB < 64KB pool.
  float* mo = (float*)pool;
  __syncthreads();                      // all tile reads done; pool reusable
  if (shard == 1) {
    #pragma unroll
    for (int db = 0; db < 2; db++)
      #pragma unroll
      for (int r = 0; r < 16; r++)
        mo[((ws * 32 + db * 16 + r) << 6) + l] = oa[db][r];
    mo[8192 + ws * 64 + l] = lsum;
  }
  __syncthreads();
  if (shard == 0) {
    const float ls2 = mo[8192 + ws * 64 + l];
    const float inv = 1.f / (lsum + ls2);
    const int b = bh >> 4, h = bh & 15;
    u16* dst = ATT + ((size_t)(b * 2048 + t_own)) * 1024 + h * 64;
    #pragma unroll
    for (int db = 0; db < 2; db++)
      #pragma unroll
      for (int rq = 0; rq < 4; rq++) {
        const int d0 = db * 32 + rq * 8 + hi * 4;
        float s0 = oa[db][4 * rq + 0] + mo[((ws * 32 + db * 16 + 4 * rq + 0) << 6) + l];
        float s1 = oa[db][4 * rq + 1] + mo[((ws * 32 + db * 16 + 4 * rq + 1) << 6) + l];
        float s2 = oa[db][4 * rq + 2] + mo[((ws * 32 + db * 16 + 4 * rq + 2) << 6) + l];
        float s3 = oa[db][4 * rq + 3] + mo[((ws * 32 + db * 16 + 4 * rq + 3) << 6) + l];
        uint2 u;
        u.x = pkbf(s0 * inv, s1 * inv);
        u.y = pkbf(s2 * inv, s3 * inv);
        *(uint2*)&dst[d0] = u;
      }
  }
}

// ------------------------------------------------- output projection (NT, bf16)
// Transposed accumulators throughout: lane holds 4 consecutive cols at fixed
// row -> vector stores (f32x4 or packed uint2). 1D grid 256, XCD-chunked:
// each XCD owns one n-tile x all 32 m-tiles (Woutt panel 256KB L2-resident).
__global__ __launch_bounds__(256) void outproj_kernel(
    const u16* __restrict__ A, const u16* __restrict__ Wt,
    const void* __restrict__ xprobe, void* __restrict__ outv)
{
  __shared__ u16 As[128 * 64];
  __shared__ u16 Bs[128 * 64];
  __shared__ int snf;
  const int tid = threadIdx.x;
  const int isb = sniff_x(xprobe, tid, &snf);
  const int bidx = blockIdx.x;
  const int n0 = (bidx & 7) * 128;      // XCD owns one n-tile
  const int m0 = (bidx >> 3) * 128;
  const int w = tid >> 6, l = tid & 63, lr = l & 15, lq = l >> 4;
  const int mrow0 = (w & 1) * 64;
  const int ncol0 = (w >> 1) * 64;
  const int srow = tid >> 3;
  const int gseg = (tid & 7) ^ (srow & 7);

  f32x4 acc[4][4] = {};

  for (int k0 = 0; k0 < 1024; k0 += 64) {
    __syncthreads();
    #pragma unroll
    for (int rd = 0; rd < 4; rd++) {
      const int row = srow + rd * 32;
      gl2lds16(A + (size_t)(m0 + row) * 1024 + k0 + gseg * 8, &As[tid * 8 + rd * 2048]);
      gl2lds16(Wt + (size_t)(n0 + row) * 1024 + k0 + gseg * 8, &Bs[tid * 8 + rd * 2048]);
    }
    __syncthreads();
    #pragma unroll
    for (int kc = 0; kc < 2; kc++) {
      bf16x8 af[4], bf[4];
      #pragma unroll
      for (int i = 0; i < 4; i++) {
        const int seg = ((kc << 2) | lq) ^ (lr & 7);
        af[i] = *(const bf16x8*)&As[(mrow0 + i * 16 + lr) * 64 + seg * 8];
        bf[i] = *(const bf16x8*)&Bs[(ncol0 + i * 16 + lr) * 64 + seg * 8];
      }
      #pragma unroll
      for (int mb = 0; mb < 4; mb++)
        #pragma unroll
        for (int nb = 0; nb < 4; nb++)
          acc[mb][nb] = __builtin_amdgcn_mfma_f32_16x16x32_bf16(bf[nb], af[mb], acc[mb][nb], 0, 0, 0);
    }
  }
  #pragma unroll
  for (int mb = 0; mb < 4; mb++) {
    const int row = m0 + mrow0 + mb * 16 + lr;
    #pragma unroll
    for (int nb = 0; nb < 4; nb++) {
      const int col = n0 + ncol0 + nb * 16 + lq * 4;
      f32x4 v = acc[mb][nb];
      if (isb) {
        uint2 uv;
        uv.x = pkbf(v[0], v[1]);
        uv.y = pkbf(v[2], v[3]);
        *(uint2*)&((u16*)outv)[(size_t)row * 1024 + col] = uv;
      } else {
        *(f32x4*)&((float*)outv)[(size_t)row * 1024 + col] = v;
      }
    }
  }
}

extern "C" void kernel_launch(void* const* d_in, const int* in_sizes, int n_in,
                              void* d_out, int out_size, void* d_ws, size_t ws_size,
                              hipStream_t stream)
{
  const void* x    = d_in[0];
  const void* wqkv = d_in[1];
  const void* wout = d_in[2];
  char* ws = (char*)d_ws;
  const size_t MB = 1024 * 1024;
  float2* CS     = (float2*)(ws + 1024);            // 512 KB
  u16*    Xb     = (u16*)(ws + 1 * MB);             // 8 MB  (aliased by ATT)
  u16*    ATT    = Xb;
  u16*    Wqkvt  = (u16*)(ws + 9 * MB);             // 6 MB
  u16*    Woutt  = (u16*)(ws + 15 * MB);            // 2 MB
  u16*    Q      = (u16*)(ws + 17 * MB);            // 8 MB
  u16*    K      = (u16*)(ws + 25 * MB);            // 8 MB
  u16*    Vt     = (u16*)(ws + 33 * MB);            // 8 MB

  prep_kernel<<<3328, 256, 0, stream>>>(x, wqkv, wout, Xb, Wqkvt, Woutt, CS);
  qkv_kernel<<<dim3(768), 256, 0, stream>>>(x, Xb, Wqkvt, CS, Q, K, Vt);
  attn_kernel<<<dim3(512), 512, 0, stream>>>(Q, K, Vt, ATT);
  outproj_kernel<<<dim3(256), 256, 0, stream>>>(ATT, Woutt, x, d_out);
}

// Round 16
// 194.616 us; speedup vs baseline: 2.0328x; 1.0086x over previous
//
#include <hip/hip_runtime.h>
#include <hip/hip_bf16.h>
#include <stdint.h>

// B=2, T=2048, D=1024, H=16, hd=64.
// R20: host-side dtype decision via in_sizes[0] (x shape fixed -> bf16 iff
// 8388608 bytes; f32=16777216; element-count semantics would read 4194304,
// which safely falls to the conservative path). xbf=1: qkv reads x directly,
// prep convert blocks exit. xbf=0: exact R17 path (prep device-sniffs and
// materializes Xb; qkv reads Xb). qkv carries NO sniff (R19's in-kernel
// sniff cost +16 VGPR/+512B LDS and ~5us). attn/outproj byte-identical to
// R17 (attn: 64-VGPR body, proven local minimum; outproj keeps device sniff
// as the authority for OUTPUT dtype).

typedef unsigned short u16;
typedef short bf16x8 __attribute__((ext_vector_type(8)));
typedef float f32x4  __attribute__((ext_vector_type(4)));
typedef float f32x16 __attribute__((ext_vector_type(16)));

#if defined(__has_builtin) && __has_builtin(__builtin_amdgcn_exp2f)
#define EXP2F(x) __builtin_amdgcn_exp2f(x)
#else
#define EXP2F(x) exp2f(x)
#endif

__device__ __forceinline__ u16 f2b(float f) {           // fp32 -> bf16 RNE
  uint32_t u = __float_as_uint(f);
  u += 0x7fffu + ((u >> 16) & 1u);
  return (u16)(u >> 16);
}
__device__ __forceinline__ uint32_t pkbf(float a, float b) {  // v_cvt_pk_bf16_f32
  __hip_bfloat162 h = __float22bfloat162_rn(make_float2(a, b));
  union { __hip_bfloat162 h2; uint32_t u; } cv; cv.h2 = h;
  return cv.u;
}

// async global->LDS DMA, 16B per lane. LDS dest must be uniform-base + lane*16.
__device__ __forceinline__ void gl2lds16(const void* g, void* l) {
  __builtin_amdgcn_global_load_lds(
      (const __attribute__((address_space(1))) unsigned int*)g,
      (__attribute__((address_space(3))) unsigned int*)l, 16, 0, 0);
}

// ------------------------------------------------- per-block dtype sniff
// Identical sample set + threshold as always (first 4096 even u16 slots of
// x) -> every block reaches the same verdict. tid in [0,256).
__device__ __forceinline__ int sniff_x(const void* x, int tid, int* sh) {
  const u16* xu = (const u16*)x;
  if (tid == 0) *sh = 0;
  __syncthreads();
  int c = 0;
  #pragma unroll
  for (int i = 0; i < 16; i++) {
    const int idx = tid + i * 256;
    float a = fabsf(__uint_as_float(((uint32_t)xu[2 * idx]) << 16));
    if (a > 1e-3f && a < 100.f) c++;
  }
  c += __shfl_down(c, 32, 64);
  c += __shfl_down(c, 16, 64);
  c += __shfl_down(c, 8, 64);
  c += __shfl_down(c, 4, 64);
  c += __shfl_down(c, 2, 64);
  c += __shfl_down(c, 1, 64);
  if ((tid & 63) == 0) atomicAdd(sh, c);
  __syncthreads();
  return (*sh > 2048) ? 1 : 0;
}

// ------------------------------------------------- 64x64 transpose helper
__device__ __forceinline__ void tr_tile(const void* src, u16* dst, int Kd, int N,
                                        int n0, int k0, int isb, u16* Lt, int tid)
{
  const int r = tid >> 2, cseg = (tid & 3) << 4;
  u16 t[16];
  if (isb) {
    const u16* s = (const u16*)src + (size_t)(k0 + r) * N + n0 + cseg;
    *(uint4*)&t[0] = *(const uint4*)s;
    *(uint4*)&t[8] = *(const uint4*)(s + 8);
  } else {
    const float* s = (const float*)src + (size_t)(k0 + r) * N + n0 + cseg;
    #pragma unroll
    for (int j = 0; j < 4; j++) {
      float4 v = *(const float4*)(s + j * 4);
      t[j*4+0] = f2b(v.x); t[j*4+1] = f2b(v.y); t[j*4+2] = f2b(v.z); t[j*4+3] = f2b(v.w);
    }
  }
  #pragma unroll
  for (int j = 0; j < 16; j++) Lt[(cseg + j) * 72 + r] = t[j];
  __syncthreads();
  const int n = tid >> 2, kseg = (tid & 3) << 4;
  uint4 u0 = *(const uint4*)&Lt[n * 72 + kseg];
  uint4 u1 = *(const uint4*)&Lt[n * 72 + kseg + 8];
  u16* d = dst + (size_t)(n0 + n) * Kd + k0 + kseg;
  *(uint4*)d = u0;
  *(uint4*)(d + 8) = u1;
}

// ------------------------------------------------- fused prep
// blocks [0,2048): x->bf16 Xb (skipped entirely when host knows x is bf16);
// [2048,2816): Wqkv^T ; [2816,3072): Wout^T ;
// [3072,3328): RoPE table CS[t*32+f] = {cos,sin}
__global__ __launch_bounds__(256) void prep_kernel(
    const void* __restrict__ x, const void* __restrict__ wqkv,
    const void* __restrict__ wout, int xbf,
    u16* __restrict__ Xb, u16* __restrict__ Wqkvt, u16* __restrict__ Woutt,
    float2* __restrict__ CS)
{
  __shared__ u16 Lt[64 * 72];
  __shared__ int snf;
  const int bid = blockIdx.x, tid = threadIdx.x;
  if (bid < 2048) {
    if (xbf) return;                    // qkv reads x directly
    const int isb = sniff_x(x, tid, &snf);
    const size_t i = ((size_t)bid * 256 + tid) * 8;
    if (isb) {
      *(uint4*)&Xb[i] = *(const uint4*)((const u16*)x + i);
    } else {
      const float* s = (const float*)x + i;
      float4 a = *(const float4*)s, b = *(const float4*)(s + 4);
      uint4 p;
      p.x = pkbf(a.x, a.y); p.y = pkbf(a.z, a.w);
      p.z = pkbf(b.x, b.y); p.w = pkbf(b.z, b.w);
      *(uint4*)&Xb[i] = p;
    }
  } else if (bid < 2816) {
    const int isb = sniff_x(x, tid, &snf);
    const int b = bid - 2048;
    tr_tile(wqkv, Wqkvt, 1024, 3072, (b % 48) * 64, (b / 48) * 64, isb, Lt, tid);
  } else if (bid < 3072) {
    const int isb = sniff_x(x, tid, &snf);
    const int b = bid - 2816;
    tr_tile(wout, Woutt, 1024, 1024, (b % 16) * 64, (b / 16) * 64, isb, Lt, tid);
  } else {
    const int idx = (bid - 3072) * 256 + tid;   // 65536
    const int t = idx >> 5, f = idx & 31;
    float invf = __expf(-(float)f * 0.2878231366242557f);  // ln(1e4)/32
    float th = (float)t * invf;
    float sn, cs;
    sincosf(th, &sn, &cs);
    CS[idx] = make_float2(cs, sn);
  }
}

// ------------------------------------------------- QKV GEMM (NT, bf16) + RoPE
// Q/K waves accumulate C^T (mfma(bf,af)): lane holds 4 consecutive d at fixed
// t -> in-lane RoPE, float4 CS loads, packed uint2 stores. V waves keep the
// original orientation; V's t-index is stored sigma4-permuted (swap bits 2<->3
// of t&15) to match the attn PV k-order. 1D grid 768, XCD-chunked: each XCD
// owns 4 m-tiles x all 24 n-tiles. A staged from Asrc (x if host-known bf16,
// else the prep-materialized Xb) -- NO device sniff here.
__global__ __launch_bounds__(256) void qkv_kernel(
    const u16* __restrict__ Asrc, const u16* __restrict__ Wt,
    const float2* __restrict__ CS,
    u16* __restrict__ Q, u16* __restrict__ K, u16* __restrict__ Vt)
{
  __shared__ u16 As[128 * 64];
  __shared__ u16 Bs[128 * 64];
  const int tid = threadIdx.x;
  const int bidx = blockIdx.x;
  const int swz = (bidx & 7) * 96 + (bidx >> 3);   // XCD-bijective, 96/XCD
  const int n0 = (swz % 24) * 128;
  const int m0 = (swz / 24) * 128;
  const int w = tid >> 6, l = tid & 63, lr = l & 15, lq = l >> 4;
  const int mrow0 = (w & 1) * 64;
  const int ncol0 = (w >> 1) * 64;
  const int srow = tid >> 3;
  const int gseg = (tid & 7) ^ (srow & 7);

  const int col0 = n0 + ncol0;
  const int sec = col0 >> 10;            // 0=q 1=k 2=v
  const int isv = (sec == 2);
  const int h = (col0 >> 6) & 15;

  f32x4 acc[4][4] = {};

  for (int k0 = 0; k0 < 1024; k0 += 64) {
    __syncthreads();
    #pragma unroll
    for (int rd = 0; rd < 4; rd++) {
      const int row = srow + rd * 32;
      gl2lds16(Asrc + (size_t)(m0 + row) * 1024 + k0 + gseg * 8, &As[tid * 8 + rd * 2048]);
      gl2lds16(Wt + (size_t)(n0 + row) * 1024 + k0 + gseg * 8, &Bs[tid * 8 + rd * 2048]);
    }
    __syncthreads();
    #pragma unroll
    for (int kc = 0; kc < 2; kc++) {
      bf16x8 af[4], bf[4];
      #pragma unroll
      for (int i = 0; i < 4; i++) {
        const int seg = ((kc << 2) | lq) ^ (lr & 7);
        af[i] = *(const bf16x8*)&As[(mrow0 + i * 16 + lr) * 64 + seg * 8];
        bf[i] = *(const bf16x8*)&Bs[(ncol0 + i * 16 + lr) * 64 + seg * 8];
      }
      if (isv) {
        #pragma unroll
        for (int mb = 0; mb < 4; mb++)
          #pragma unroll
          for (int nb = 0; nb < 4; nb++)
            acc[mb][nb] = __builtin_amdgcn_mfma_f32_16x16x32_bf16(af[mb], bf[nb], acc[mb][nb], 0, 0, 0);
      } else {
        // transposed: rows = n (d), cols = m (t)
        #pragma unroll
        for (int mb = 0; mb < 4; mb++)
          #pragma unroll
          for (int nb = 0; nb < 4; nb++)
            acc[mb][nb] = __builtin_amdgcn_mfma_f32_16x16x32_bf16(bf[nb], af[mb], acc[mb][nb], 0, 0, 0);
      }
    }
  }

  if (isv) {
    #pragma unroll
    for (int mb = 0; mb < 4; mb++) {
      const int row0 = m0 + mrow0 + mb * 16 + lq * 4;
      const int b = row0 >> 11, t0 = row0 & 2047;
      // sigma4: swap bits 2 and 3 of t (t0 is a multiple of 4):
      const int tp = (t0 & ~12) | ((t0 & 4) << 1) | ((t0 & 8) >> 1);
      #pragma unroll
      for (int nb = 0; nb < 4; nb++) {
        const int d = nb * 16 + lr;
        uint2 uv;
        uv.x = pkbf(acc[mb][nb][0], acc[mb][nb][1]);
        uv.y = pkbf(acc[mb][nb][2], acc[mb][nb][3]);
        *(uint2*)&Vt[(((size_t)b * 16 + h) * 64 + d) * 2048 + tp] = uv;
      }
    }
  } else {
    u16* dst = (sec == 0) ? Q : K;
    const float qscale = 0.125f * 1.44269504f;   // 1/sqrt(hd) * log2(e), q only
    #pragma unroll
    for (int mb = 0; mb < 4; mb++) {
      const int m = m0 + mrow0 + mb * 16 + lr;   // global row = b*2048 + t
      const int b = m >> 11, t = m & 2047;
      const float* csrow = (const float*)(CS + t * 32);
      #pragma unroll
      for (int nb = 0; nb < 4; nb++) {
        const int d = nb * 16 + lq * 4;          // 4 consecutive d, d%4==0
        const int fb = d & 31;                   // pair block stays within 32
        f32x4 c01 = *(const f32x4*)(csrow + 2 * fb);      // {c0,s0,c1,s1}
        f32x4 c23 = *(const f32x4*)(csrow + 2 * fb + 4);  // {c2,s2,c3,s3}
        float v0 = acc[mb][nb][0], v1 = acc[mb][nb][1];
        float v2 = acc[mb][nb][2], v3 = acc[mb][nb][3];
        float r0 = v0 * c01[0] - v1 * c01[1];
        float r1 = fmaf(v1, c01[2], v0 * c01[3]);
        float r2 = v2 * c23[0] - v3 * c23[1];
        float r3 = fmaf(v3, c23[2], v2 * c23[3]);
        if (sec == 0) { r0 *= qscale; r1 *= qscale; r2 *= qscale; r3 *= qscale; }
        uint2 uv;
        uv.x = pkbf(r0, r1);
        uv.y = pkbf(r2, r3);
        *(uint2*)&dst[(((size_t)b * 16 + h) * 2048 + t) * 64 + d] = uv;
      }
    }
  }
}

// ------------------------------------------------- MFMA flash attention (R12)
// Block = 8 waves (512 thr): shard = wave>>2 picks the s-half; subwave ws =
// wave&3 picks 32 q-rows of the block's 128. Each shard double-buffers its
// own K/V (pool 64KB). 32x32x16 MFMA, lane owns one q-row; sigma4-permuted
// Vt makes S^T C-regs the PV B-operand. Partials merged via LDS -> ATT.
// NOTE: live state exactly fits the 64-VGPR budget this launch_bounds pins;
// any additional accumulator state spills to scratch (R18: 5x slowdown).
__global__ __launch_bounds__(512, 4) void attn_kernel(
    const u16* __restrict__ Q, const u16* __restrict__ K,
    const u16* __restrict__ Vt, u16* __restrict__ ATT)
{
  __shared__ u16 pool[2][2][2][4096];   // [shard][K=0/V=1][buf][64*64] = 64KB
  const int tid = threadIdx.x;          // 0..511
  const int shard = tid >> 8;
  const int t2 = tid & 255;             // tid within shard
  const int ws = (tid >> 6) & 3;        // subwave (q-group)
  const int l = tid & 63;
  const int m5 = l & 31, hi = l >> 5;

  // XCD-bijective swizzle: grid 512 = 32 bh x 16 qt; 64 consecutive work ids
  // (4 bh) per XCD.
  const int bid = blockIdx.x;
  const int swz = (bid & 7) * 64 + (bid >> 3);
  const int bh = swz >> 4;
  const int qt = swz & 15;

  const int sbeg = shard * 1024;        // this shard's s-range
  const size_t base = (size_t)bh * (2048 * 64);
  const int qrow0 = qt * 128 + ws * 32;
  const int t_own = qrow0 + m5;         // this lane's q-row

  // Q fragments (B-operand: col = m5, k-slot hi*8+j = d kd*16+hi*8+j)
  bf16x8 qf[4];
  #pragma unroll
  for (int kd = 0; kd < 4; kd++)
    qf[kd] = *(const bf16x8*)(Q + base + (size_t)t_own * 64 + kd * 16 + hi * 8);

  f32x16 oa[2] = {};                    // O^T partial: rows d = db*32+C-row
  float lsum = 0.f;

  const int srow = t2 >> 3;

  auto stage = [&](int buf, int s0) {
    #pragma unroll
    for (int rd = 0; rd < 2; rd++) {
      const int row = srow + rd * 32;
      const int gs = (t2 & 7) ^ (row & 7) ^ ((row >> 3) & 3);
      gl2lds16(K + base + (size_t)(s0 + row) * 64 + gs * 8,
               &pool[shard][0][buf][t2 * 8 + rd * 2048]);
      gl2lds16(Vt + base + (size_t)row * 2048 + s0 + gs * 8,
               &pool[shard][1][buf][t2 * 8 + rd * 2048]);
    }
  };

  stage(0, sbeg);
  const int nt = 16;

  #pragma unroll 1
  for (int t = 0; t < nt; t++) {
    const int buf = t & 1;
    __syncthreads();                    // drains DMA for buf, fences prev reads
    if (t + 1 < nt) stage(buf ^ 1, sbeg + (t + 1) * 64);
    const u16* Ks = pool[shard][0][buf];
    const u16* Vs = pool[shard][1][buf];

    // ---- S phase: per s-block of 32, kf row = sb*32+m5, d-seg (kd<<1)|hi
    uint32_t pw[2][8];
    #pragma unroll
    for (int sb = 0; sb < 2; sb++) {
      const int row = sb * 32 + m5;
      const int sw = (row & 7) ^ ((row >> 3) & 3);
      bf16x8 kf[4];
      #pragma unroll
      for (int kd = 0; kd < 4; kd++)
        kf[kd] = *(const bf16x8*)&Ks[row * 64 + ((((kd << 1) | hi) ^ sw) << 3)];
      f32x16 z = {};
      __builtin_amdgcn_s_setprio(1);
      z = __builtin_amdgcn_mfma_f32_32x32x16_bf16(kf[0], qf[0], z, 0, 0, 0);
      z = __builtin_amdgcn_mfma_f32_32x32x16_bf16(kf[1], qf[1], z, 0, 0, 0);
      z = __builtin_amdgcn_mfma_f32_32x32x16_bf16(kf[2], qf[2], z, 0, 0, 0);
      z = __builtin_amdgcn_mfma_f32_32x32x16_bf16(kf[3], qf[3], z, 0, 0, 0);
      __builtin_amdgcn_s_setprio(0);
      float e[16];
      #pragma unroll
      for (int r = 0; r < 16; r++) e[r] = EXP2F(z[r]);
      lsum += (((e[0] + e[1]) + (e[2] + e[3])) + ((e[4] + e[5]) + (e[6] + e[7])))
            + (((e[8] + e[9]) + (e[10] + e[11])) + ((e[12] + e[13]) + (e[14] + e[15])));
      #pragma unroll
      for (int w2 = 0; w2 < 8; w2++)
        pw[sb][w2] = pkbf(e[2 * w2], e[2 * w2 + 1]);
    }

    // ---- PV phase: vf row = db*32+m5, t-seg (sblk<<1)|hi (sigma4-linear)
    #pragma unroll
    for (int db = 0; db < 2; db++) {
      const int row = db * 32 + m5;
      const int sw = (row & 7) ^ ((row >> 3) & 3);
      bf16x8 vf[4];
      #pragma unroll
      for (int sblk = 0; sblk < 4; sblk++)
        vf[sblk] = *(const bf16x8*)&Vs[row * 64 + ((((sblk << 1) | hi) ^ sw) << 3)];
      __builtin_amdgcn_s_setprio(1);
      #pragma unroll
      for (int sblk = 0; sblk < 4; sblk++) {
        union { uint32_t u[4]; bf16x8 v; } pf;
        const int sb = sblk >> 1, off = (sblk & 1) * 4;
        pf.u[0] = pw[sb][off + 0]; pf.u[1] = pw[sb][off + 1];
        pf.u[2] = pw[sb][off + 2]; pf.u[3] = pw[sb][off + 3];
        oa[db] = __builtin_amdgcn_mfma_f32_32x32x16_bf16(vf[sblk], pf.v, oa[db], 0, 0, 0);
      }
      __builtin_amdgcn_s_setprio(0);
    }
  }

  // reduce row sum across the hi pair (lanes l and l+32 share t_own)
  lsum += __shfl_xor(lsum, 32, 64);

  // ---- in-block merge: shard 1 dumps partials to LDS, shard 0 combines.
  // Layout mo[(ws*32 + r)*64 + lane] (lane-contiguous -> conflict-free);
  // lsum at float offset 8192 + ws*64 + lane. 33KB < 64KB pool.
  float* mo = (float*)pool;
  __syncthreads();                      // all tile reads done; pool reusable
  if (shard == 1) {
    #pragma unroll
    for (int db = 0; db < 2; db++)
      #pragma unroll
      for (int r = 0; r < 16; r++)
        mo[((ws * 32 + db * 16 + r) << 6) + l] = oa[db][r];
    mo[8192 + ws * 64 + l] = lsum;
  }
  __syncthreads();
  if (shard == 0) {
    const float ls2 = mo[8192 + ws * 64 + l];
    const float inv = 1.f / (lsum + ls2);
    const int b = bh >> 4, h = bh & 15;
    u16* dst = ATT + ((size_t)(b * 2048 + t_own)) * 1024 + h * 64;
    #pragma unroll
    for (int db = 0; db < 2; db++)
      #pragma unroll
      for (int rq = 0; rq < 4; rq++) {
        const int d0 = db * 32 + rq * 8 + hi * 4;
        float s0 = oa[db][4 * rq + 0] + mo[((ws * 32 + db * 16 + 4 * rq + 0) << 6) + l];
        float s1 = oa[db][4 * rq + 1] + mo[((ws * 32 + db * 16 + 4 * rq + 1) << 6) + l];
        float s2 = oa[db][4 * rq + 2] + mo[((ws * 32 + db * 16 + 4 * rq + 2) << 6) + l];
        float s3 = oa[db][4 * rq + 3] + mo[((ws * 32 + db * 16 + 4 * rq + 3) << 6) + l];
        uint2 u;
        u.x = pkbf(s0 * inv, s1 * inv);
        u.y = pkbf(s2 * inv, s3 * inv);
        *(uint2*)&dst[d0] = u;
      }
  }
}

// ------------------------------------------------- output projection (NT, bf16)
// Transposed accumulators throughout: lane holds 4 consecutive cols at fixed
// row -> vector stores (f32x4 or packed uint2). 1D grid 256, XCD-chunked:
// each XCD owns one n-tile x all 32 m-tiles (Woutt panel 256KB L2-resident).
__global__ __launch_bounds__(256) void outproj_kernel(
    const u16* __restrict__ A, const u16* __restrict__ Wt,
    const void* __restrict__ xprobe, void* __restrict__ outv)
{
  __shared__ u16 As[128 * 64];
  __shared__ u16 Bs[128 * 64];
  __shared__ int snf;
  const int tid = threadIdx.x;
  const int isb = sniff_x(xprobe, tid, &snf);
  const int bidx = blockIdx.x;
  const int n0 = (bidx & 7) * 128;      // XCD owns one n-tile
  const int m0 = (bidx >> 3) * 128;
  const int w = tid >> 6, l = tid & 63, lr = l & 15, lq = l >> 4;
  const int mrow0 = (w & 1) * 64;
  const int ncol0 = (w >> 1) * 64;
  const int srow = tid >> 3;
  const int gseg = (tid & 7) ^ (srow & 7);

  f32x4 acc[4][4] = {};

  for (int k0 = 0; k0 < 1024; k0 += 64) {
    __syncthreads();
    #pragma unroll
    for (int rd = 0; rd < 4; rd++) {
      const int row = srow + rd * 32;
      gl2lds16(A + (size_t)(m0 + row) * 1024 + k0 + gseg * 8, &As[tid * 8 + rd * 2048]);
      gl2lds16(Wt + (size_t)(n0 + row) * 1024 + k0 + gseg * 8, &Bs[tid * 8 + rd * 2048]);
    }
    __syncthreads();
    #pragma unroll
    for (int kc = 0; kc < 2; kc++) {
      bf16x8 af[4], bf[4];
      #pragma unroll
      for (int i = 0; i < 4; i++) {
        const int seg = ((kc << 2) | lq) ^ (lr & 7);
        af[i] = *(const bf16x8*)&As[(mrow0 + i * 16 + lr) * 64 + seg * 8];
        bf[i] = *(const bf16x8*)&Bs[(ncol0 + i * 16 + lr) * 64 + seg * 8];
      }
      #pragma unroll
      for (int mb = 0; mb < 4; mb++)
        #pragma unroll
        for (int nb = 0; nb < 4; nb++)
          acc[mb][nb] = __builtin_amdgcn_mfma_f32_16x16x32_bf16(bf[nb], af[mb], acc[mb][nb], 0, 0, 0);
    }
  }
  #pragma unroll
  for (int mb = 0; mb < 4; mb++) {
    const int row = m0 + mrow0 + mb * 16 + lr;
    #pragma unroll
    for (int nb = 0; nb < 4; nb++) {
      const int col = n0 + ncol0 + nb * 16 + lq * 4;
      f32x4 v = acc[mb][nb];
      if (isb) {
        uint2 uv;
        uv.x = pkbf(v[0], v[1]);
        uv.y = pkbf(v[2], v[3]);
        *(uint2*)&((u16*)outv)[(size_t)row * 1024 + col] = uv;
      } else {
        *(f32x4*)&((float*)outv)[(size_t)row * 1024 + col] = v;
      }
    }
  }
}

extern "C" void kernel_launch(void* const* d_in, const int* in_sizes, int n_in,
                              void* d_out, int out_size, void* d_ws, size_t ws_size,
                              hipStream_t stream)
{
  const void* x    = d_in[0];
  const void* wqkv = d_in[1];
  const void* wout = d_in[2];
  char* ws = (char*)d_ws;
  const size_t MB = 1024 * 1024;
  float2* CS     = (float2*)(ws + 1024);            // 512 KB
  u16*    Xb     = (u16*)(ws + 1 * MB);             // 8 MB  (aliased by ATT)
  u16*    ATT    = Xb;
  u16*    Wqkvt  = (u16*)(ws + 9 * MB);             // 6 MB
  u16*    Woutt  = (u16*)(ws + 15 * MB);            // 2 MB
  u16*    Q      = (u16*)(ws + 17 * MB);            // 8 MB
  u16*    K      = (u16*)(ws + 25 * MB);            // 8 MB
  u16*    Vt     = (u16*)(ws + 33 * MB);            // 8 MB

  // Host-side dtype decision: x has fixed shape (2,2048,1024); bf16 iff its
  // byte size is 8388608. Any other value (f32 = 16777216, or element-count
  // semantics = 4194304) falls to the conservative prep->Xb path.
  const int xbf = (in_sizes && in_sizes[0] == 8388608) ? 1 : 0;
  const u16* Asrc = xbf ? (const u16*)x : Xb;

  prep_kernel<<<3328, 256, 0, stream>>>(x, wqkv, wout, xbf, Xb, Wqkvt, Woutt, CS);
  qkv_kernel<<<dim3(768), 256, 0, stream>>>(Asrc, Wqkvt, CS, Q, K, Vt);
  attn_kernel<<<dim3(512), 512, 0, stream>>>(Q, K, Vt, ATT);
  outproj_kernel<<<dim3(256), 256, 0, stream>>>(ATT, Woutt, x, d_out);
}